// Round 19
// baseline (152.243 us; speedup 1.0000x reference)
//
#include <hip/hip_runtime.h>
#include <math.h>

#define BATCH 2
#define CH    192
#define NPTS  8192
#define KNN   9

#define NT     64      // rows per normalize block
#define TLIST  8       // per-lane candidate list depth
#define NT32   256     // 32-wide point tiles per batch
#define KS     12      // 192 / 16
#define CSPLIT 32      // cand-space splits (phase 1)
#define NITER  (NT32 / CSPLIT)   // 8
#define NCANDP 512     // packed candidates per query (32 cs * 2 h * 8)
#define P2ROWS 4       // phase-2 rows per block (1 per wave)
#define NSEL   12      // candidates exactly re-ranked per row

typedef __attribute__((ext_vector_type(8)))  short  bf16x8;
typedef __attribute__((ext_vector_type(8)))  unsigned short u16x8;
typedef __attribute__((ext_vector_type(16))) float  f32x16;

static __device__ __forceinline__ unsigned short f2bf(float f) {
    unsigned u = __float_as_uint(f);
    u += 0x7fffu + ((u >> 16) & 1u);          // round-to-nearest-even
    return (unsigned short)(u >> 16);
}
static __device__ __forceinline__ bf16x8 negbf(bf16x8 v) {
    bf16x8 r;
    #pragma unroll
    for (int e = 0; e < 8; ++e) r[e] = (short)(v[e] ^ (short)0x8000);
    return r;
}
static __device__ __forceinline__ unsigned umax2(unsigned a, unsigned b) {
    return a > b ? a : b;
}
static __device__ __forceinline__ unsigned umin2(unsigned a, unsigned b) {
    return a < b ? a : b;
}

// ---------------------------------------------------------------------------
// Kernel A: norms + layouts (unchanged — passing since R13).
//  pk [B][tile32(256)][ks(12)][lane(64)*8] bf16
//     element: point = tile32*32 + (lane&31), k = ks*16 + (lane>>5)*8 + e
//  x_rm [B][N][C] f32 raw; rdnd/ssd f64 per point.
// ---------------------------------------------------------------------------
__global__ __launch_bounds__(256) void knn_normalize(
    const float* __restrict__ x,
    unsigned short* __restrict__ pk, float* __restrict__ x_rm,
    double* __restrict__ rdnd, double* __restrict__ ssd)
{
    __shared__ float  tile[CH][NT + 1];
    __shared__ double rdn_sh[NT];

    const int b   = blockIdx.x >> 7;
    const int rb  = blockIdx.x & 127;
    const int n0  = rb << 6;
    const int tid = threadIdx.x;
    const float* xb = x + (size_t)b * CH * NPTS;

    #pragma unroll
    for (int i = 0; i < (CH * NT) / 256; ++i) {
        int flat = tid + i * 256;
        int c = flat >> 6, j = flat & 63;
        tile[c][j] = xb[(size_t)c * NPTS + n0 + j];
    }
    __syncthreads();

    // 4 threads per point: quarter q covers dims q*48..q*48+47
    {
        const int j = tid >> 2, q = tid & 3;
        double ss = 0.0;
        #pragma unroll 8
        for (int c = 0; c < 48; ++c) {
            double v = (double)tile[q * 48 + c][j];
            ss = fma(v, v, ss);
        }
        ss += __shfl_xor(ss, 1, 64);
        ss += __shfl_xor(ss, 2, 64);
        if (q == 0) {
            double dn = sqrt(ss);
            if (dn < 1e-12) dn = 1e-12;
            double rdn = 1.0 / dn;
            rdn_sh[j] = rdn;
            rdnd[b * NPTS + n0 + j] = rdn;
            ssd [b * NPTS + n0 + j] = ss;
        }
    }
    __syncthreads();

    // packed MFMA-frag bf16 (2 tile32s * 12 ksteps = 24 frags/block)
    #pragma unroll
    for (int i = 0; i < 6; ++i) {
        int pid  = tid + i * 256;
        int frag = pid >> 6;              // 0..23
        int lane = pid & 63;
        int tl   = frag / KS;             // 0..1
        int ks   = frag - tl * KS;        // 0..11
        int rl   = (tl << 5) + (lane & 31);          // local point 0..63
        int kb   = (ks << 4) + ((lane >> 5) << 3);   // k base
        double rdn = rdn_sh[rl];
        u16x8 hv;
        #pragma unroll
        for (int e = 0; e < 8; ++e) {
            float v = (float)((double)tile[kb + e][rl] * rdn);
            hv[e] = f2bf(v);
        }
        size_t base = ((size_t)((b * NT32 + (rb << 1) + tl) * KS + ks)) * 512
                      + ((size_t)lane << 3);
        *(u16x8*)(pk + base) = hv;
    }

    #pragma unroll
    for (int i = 0; i < (CH * NT) / 256; ++i) {
        int flat = tid + i * 256;
        int j = flat / CH, c = flat - j * CH;
        x_rm[(size_t)(b * NPTS + n0 + j) * CH + c] = tile[c][j];
    }
}

// ---------------------------------------------------------------------------
// Phase 1 v15: R16 structure (no-LDS global->reg stream, sorted-ladder,
// lane owns 1 query + 1 depth-8 list) with CSPLIT 32: each block covers
// 256 cands/query (8 iters) -> per-lane selection keys halve (128 vs 256).
// Total MFMA unchanged (2x blocks x 1/2 iters). Buckets/query = 64
// (safer: lambda = 8/64). Grid 4096 = B(2) x qb(64) x cs(32).
// ---------------------------------------------------------------------------
__global__ __attribute__((amdgpu_flat_work_group_size(256, 256),
                          amdgpu_waves_per_eu(4, 4)))
void knn_phase1(
    const unsigned short* __restrict__ pk,
    unsigned* __restrict__ cand_p)
{
    const int bid  = blockIdx.x;          // 4096
    const int b    = bid >> 11;
    const int r11  = bid & 2047;
    const int qb   = r11 >> 5;            // query block 0..63 (128 queries)
    const int cs   = r11 & 31;            // cand split 0..31 (256 cands)
    const int tid  = threadIdx.x;
    const int wave = tid >> 6;            // 0..3
    const int lane = tid & 63;
    const unsigned short* pkb = pk + (size_t)b * (NT32 * KS * 512);

    // query fragments (B operand), negated for acc = 4 - inner
    const int qt = qb * 4 + wave;         // query tile32 0..255
    bf16x8 qf[KS];
    #pragma unroll
    for (int ks = 0; ks < KS; ++ks) {
        const unsigned short* p = pkb + ((size_t)(qt * KS + ks)) * 512 + (lane << 3);
        qf[ks] = negbf(*(const bf16x8*)p);
    }
    #pragma unroll
    for (int ks = 0; ks < KS; ++ks)
        asm volatile("" : "+a"(qf[ks]));   // MFMA-only operand: AGPR class

    // sorted-ascending list; sentinels above all real keys (real < 0x40D00000)
    unsigned lst[TLIST];
    #pragma unroll
    for (int t = 0; t < TLIST; ++t) lst[t] = 0xFFFFFF00u | t;

    const unsigned short* gbase = pkb + (size_t)(cs * NITER) * (KS * 512) + (lane << 3);

    for (int it = 0; it < NITER; ++it) {
        const unsigned short* gt = gbase + (size_t)it * (KS * 512);

        f32x16 acc;
        #pragma unroll
        for (int r = 0; r < 16; ++r) acc[r] = 4.f;

        #pragma unroll
        for (int ks = 0; ks < KS; ++ks) {
            bf16x8 cf = *(const bf16x8*)(gt + (ks << 9));
            acc = __builtin_amdgcn_mfma_f32_32x32x16_bf16(cf, qf[ks], acc, 0, 0, 0);
        }

        // sorted-ladder selection: key = 4 - inner (positive -> uint order)
        // packed = (bits & ~0xFF) | (it<<4) | reg ; payload makes keys unique
        const unsigned pb = (unsigned)(it << 4);
        #pragma unroll
        for (int r = 0; r < 16; ++r) {
            unsigned hi = (__float_as_uint(acc[r]) & 0xFFFFFF00u) | pb | (unsigned)r;
            #pragma unroll
            for (int t = 0; t < TLIST; ++t) {
                unsigned lo = umin2(lst[t], hi);
                hi = umax2(lst[t], hi);
                lst[t] = lo;
            }
        }
        // keep list in arch VGPRs at the loop back-edge
        asm volatile("" : "+v"(lst[0]), "+v"(lst[1]), "+v"(lst[2]), "+v"(lst[3]),
                          "+v"(lst[4]), "+v"(lst[5]), "+v"(lst[6]), "+v"(lst[7]));
    }

    // write: [B*N query][cs(32)][h(2)][8]  (list is sorted ascending)
    const int query = (qt << 5) + (lane & 31);
    const int h     = lane >> 5;
    unsigned* dst = cand_p + ((size_t)(b * NPTS + query) << 9) + (cs << 4) + (h << 3);
    uint4 w0 = make_uint4(lst[0], lst[1], lst[2], lst[3]);
    uint4 w1 = make_uint4(lst[4], lst[5], lst[6], lst[7]);
    *(uint4*)dst       = w0;
    *(uint4*)(dst + 4) = w1;
}

// ---------------------------------------------------------------------------
// Phase 2: 1 query per wave, 4 per block, 4096 blocks. NSEL=12.
//  (a) per-lane 8 packed cands (one (cs,h) bucket, 2x uint4), sort8 (19 CE),
//      12-round wave-min extraction
//  (b) f64 re-rank (12 cands): lane=(cand,quarter), float4 gathers, 2-shfl
//  (c) parallel rank-of-12: each lane counts lex-smaller keys, writes
//      out[rank] directly
// ---------------------------------------------------------------------------
__global__ __launch_bounds__(256) void knn_phase2(
    const float* __restrict__ x_rm,
    const double* __restrict__ rdnd, const double* __restrict__ ssd,
    const unsigned* __restrict__ cand_p,
    int* __restrict__ out)
{
    __shared__ double xc[P2ROWS][CH];     // 6144 B
    __shared__ int    sel[P2ROWS][16];
    __shared__ double dks[P2ROWS][16];

    const int bi   = blockIdx.x;          // 4096
    const int b    = bi >> 11;
    const int r0   = (bi & 2047) << 2;
    const int tid  = threadIdx.x;
    const int wave = tid >> 6;
    const int lane = tid & 63;
    const int bN   = b * NPTS;

    for (int i = tid; i < P2ROWS * CH; i += 256) {
        int r = i / CH, c = i - r * CH;
        xc[r][c] = (double)x_rm[(size_t)(bN + r0 + r) * CH + c] * rdnd[bN + r0 + r];
    }
    __syncthreads();

    const int row = r0 + wave;

    // (a) lane's bucket: cs = lane>>1, h = lane&1; 8 packed u32 -> u64
    unsigned long long qq[8];
    {
        const unsigned* cp = cand_p + ((size_t)(bN + row) << 9) + (lane << 3);
        uint4 pv0 = *(const uint4*)cp;
        uint4 pv1 = *(const uint4*)(cp + 4);
        unsigned pk8[8] = {pv0.x, pv0.y, pv0.z, pv0.w, pv1.x, pv1.y, pv1.z, pv1.w};
        const int cs = lane >> 1, h = lane & 1;
        #pragma unroll
        for (int u = 0; u < 8; ++u) {
            unsigned pkv = pk8[u];
            int r = (int)(pkv & 15u), ct = (int)((pkv >> 4) & 7u);
            int rowc = (r & 3) + ((r >> 2) << 3) + (h << 2);
            int col  = (cs << 8) + (ct << 5) + rowc;
            qq[u] = ((unsigned long long)pkv << 32) | (unsigned)col;
        }
        // Batcher odd-even merge sort 8 ascending (19 CE)
        unsigned long long t;
        #define CE(a, b) if (qq[b] < qq[a]) { t = qq[a]; qq[a] = qq[b]; qq[b] = t; }
        CE(0,1) CE(2,3) CE(4,5) CE(6,7)
        CE(0,2) CE(1,3) CE(4,6) CE(5,7)
        CE(1,2) CE(5,6)
        CE(0,4) CE(1,5) CE(2,6) CE(3,7)
        CE(2,4) CE(3,5)
        CE(1,2) CE(3,4) CE(5,6)
        #undef CE
    }

    // NSEL extraction rounds of wave-wide u64 min; lane r captures round r
    unsigned long long my_sel = 0;
    #pragma unroll
    for (int round = 0; round < NSEL; ++round) {
        unsigned long long m = qq[0];
        #pragma unroll
        for (int off = 1; off < 64; off <<= 1) {
            unsigned long long o = __shfl_xor(m, off, 64);
            m = (o < m) ? o : m;
        }
        if (qq[0] == m) {                 // exactly one lane (u64 unique via col)
            #pragma unroll
            for (int u = 0; u < 7; ++u) qq[u] = qq[u + 1];
            qq[7] = 0xFFFFFFFFFFFFFFFFull;
        }
        if (lane == round) my_sel = m;
    }
    if (lane < NSEL) sel[wave][lane] = (int)((unsigned)my_sel & 0x3FFFu);
    __builtin_amdgcn_wave_barrier();

    // (b) exact f64 keys: lane = (cand c, quarter qd), c < NSEL active
    {
        const int c = lane & 15, qd = lane >> 4;
        if (c < NSEL) {
            const int m = sel[wave][c];
            const double rdm = rdnd[bN + m];
            const float* xr = x_rm + (size_t)(bN + m) * CH + qd * 48;
            const double* xcp = &xc[wave][qd * 48];
            double s0 = 0.0, s1 = 0.0, s2 = 0.0, s3 = 0.0;
            #pragma unroll
            for (int j = 0; j < 12; ++j) {
                float4 v = *(const float4*)(xr + (j << 2));
                s0 = fma((double)v.x * rdm, xcp[(j << 2) + 0], s0);
                s1 = fma((double)v.y * rdm, xcp[(j << 2) + 1], s1);
                s2 = fma((double)v.z * rdm, xcp[(j << 2) + 2], s2);
                s3 = fma((double)v.w * rdm, xcp[(j << 2) + 3], s3);
            }
            double dot = (s0 + s1) + (s2 + s3);
            dot += __shfl_xor(dot, 16, 64);
            dot += __shfl_xor(dot, 32, 64);
            if (qd == 0) dks[wave][c] = fma(-2.0, dot, ssd[bN + m] * rdm * rdm);
        } else {
            double dot = 0.0;             // keep shuffles wave-uniform
            dot += __shfl_xor(dot, 16, 64);
            dot += __shfl_xor(dot, 32, 64);
        }
    }
    __builtin_amdgcn_wave_barrier();

    // (c) parallel rank: lane c < NSEL counts lex-smaller keys; rank < 9 wins
    if (lane < NSEL) {
        const double dm = dks[wave][lane];
        const int    sm = sel[wave][lane];
        int cnt = 0;
        #pragma unroll
        for (int s = 0; s < NSEL; ++s) {
            double d = dks[wave][s]; int m = sel[wave][s];
            cnt += (d < dm || (d == dm && m < sm)) ? 1 : 0;
        }
        if (cnt < KNN) {
            const int n = row;
            out[(size_t)(bN + n) * KNN + cnt] = sm;
            out[(size_t)BATCH * NPTS * KNN + (size_t)(bN + n) * KNN + cnt] = n;
        }
    }
}

// ---------------------------------------------------------------------------
extern "C" void kernel_launch(void* const* d_in, const int* in_sizes, int n_in,
                              void* d_out, int out_size, void* d_ws, size_t ws_size,
                              hipStream_t stream)
{
    const float* x = (const float*)d_in[0];
    int* out = (int*)d_out;

    char* ws = (char*)d_ws;
    const size_t sz_pk  = (size_t)BATCH * NT32 * KS * 512 * sizeof(unsigned short); // 6.29 MB
    const size_t sz_xrm = (size_t)BATCH * NPTS * CH * sizeof(float);                // 12.58 MB
    const size_t sz_rdn = (size_t)BATCH * NPTS * sizeof(double);
    const size_t sz_ss  = sz_rdn;

    unsigned short* pk = (unsigned short*)(ws);
    float*  x_rm   = (float*) (ws + sz_pk);
    double* rdnd   = (double*)(ws + sz_pk + sz_xrm);
    double* ssd    = (double*)(ws + sz_pk + sz_xrm + sz_rdn);
    unsigned* cand_p = (unsigned*)(ws + sz_pk + sz_xrm + sz_rdn + sz_ss);           // 33.6 MB

    knn_normalize<<<BATCH * (NPTS / NT), 256, 0, stream>>>(x, pk, x_rm, rdnd, ssd);
    knn_phase1  <<<BATCH * 64 * CSPLIT, 256, 0, stream>>>(pk, cand_p);
    knn_phase2  <<<BATCH * (NPTS / P2ROWS), 256, 0, stream>>>(x_rm, rdnd, ssd, cand_p, out);
}

// Round 20
// 145.067 us; speedup vs baseline: 1.0495x; 1.0495x over previous
//
#include <hip/hip_runtime.h>
#include <math.h>

#define BATCH 2
#define CH    192
#define NPTS  8192
#define KNN   9

#define NT     64      // rows per normalize block
#define TLIST  6       // per-lane candidate list depth
#define NT32   256     // 32-wide point tiles per batch
#define KS     12      // 192 / 16
#define CSPLIT 32      // cand-space splits (phase 1)
#define NITER  (NT32 / CSPLIT)   // 8
#define NCANDP 384     // packed candidates per query (32 cs * 2 h * 6)
#define P2ROWS 4       // phase-2 rows per block (1 per wave)
#define NSEL   12      // candidates exactly re-ranked per row

typedef __attribute__((ext_vector_type(8)))  short  bf16x8;
typedef __attribute__((ext_vector_type(8)))  unsigned short u16x8;
typedef __attribute__((ext_vector_type(16))) float  f32x16;

static __device__ __forceinline__ unsigned short f2bf(float f) {
    unsigned u = __float_as_uint(f);
    u += 0x7fffu + ((u >> 16) & 1u);          // round-to-nearest-even
    return (unsigned short)(u >> 16);
}
static __device__ __forceinline__ bf16x8 negbf(bf16x8 v) {
    bf16x8 r;
    #pragma unroll
    for (int e = 0; e < 8; ++e) r[e] = (short)(v[e] ^ (short)0x8000);
    return r;
}
static __device__ __forceinline__ unsigned umax2(unsigned a, unsigned b) {
    return a > b ? a : b;
}
static __device__ __forceinline__ unsigned umin2(unsigned a, unsigned b) {
    return a < b ? a : b;
}

// ---------------------------------------------------------------------------
// Kernel A: norms + layouts (unchanged — passing since R13).
//  pk [B][tile32(256)][ks(12)][lane(64)*8] bf16
//     element: point = tile32*32 + (lane&31), k = ks*16 + (lane>>5)*8 + e
//  x_rm [B][N][C] f32 raw; rdnd/ssd f64 per point.
// ---------------------------------------------------------------------------
__global__ __launch_bounds__(256) void knn_normalize(
    const float* __restrict__ x,
    unsigned short* __restrict__ pk, float* __restrict__ x_rm,
    double* __restrict__ rdnd, double* __restrict__ ssd)
{
    __shared__ float  tile[CH][NT + 1];
    __shared__ double rdn_sh[NT];

    const int b   = blockIdx.x >> 7;
    const int rb  = blockIdx.x & 127;
    const int n0  = rb << 6;
    const int tid = threadIdx.x;
    const float* xb = x + (size_t)b * CH * NPTS;

    #pragma unroll
    for (int i = 0; i < (CH * NT) / 256; ++i) {
        int flat = tid + i * 256;
        int c = flat >> 6, j = flat & 63;
        tile[c][j] = xb[(size_t)c * NPTS + n0 + j];
    }
    __syncthreads();

    // 4 threads per point: quarter q covers dims q*48..q*48+47
    {
        const int j = tid >> 2, q = tid & 3;
        double ss = 0.0;
        #pragma unroll 8
        for (int c = 0; c < 48; ++c) {
            double v = (double)tile[q * 48 + c][j];
            ss = fma(v, v, ss);
        }
        ss += __shfl_xor(ss, 1, 64);
        ss += __shfl_xor(ss, 2, 64);
        if (q == 0) {
            double dn = sqrt(ss);
            if (dn < 1e-12) dn = 1e-12;
            double rdn = 1.0 / dn;
            rdn_sh[j] = rdn;
            rdnd[b * NPTS + n0 + j] = rdn;
            ssd [b * NPTS + n0 + j] = ss;
        }
    }
    __syncthreads();

    // packed MFMA-frag bf16 (2 tile32s * 12 ksteps = 24 frags/block)
    #pragma unroll
    for (int i = 0; i < 6; ++i) {
        int pid  = tid + i * 256;
        int frag = pid >> 6;              // 0..23
        int lane = pid & 63;
        int tl   = frag / KS;             // 0..1
        int ks   = frag - tl * KS;        // 0..11
        int rl   = (tl << 5) + (lane & 31);          // local point 0..63
        int kb   = (ks << 4) + ((lane >> 5) << 3);   // k base
        double rdn = rdn_sh[rl];
        u16x8 hv;
        #pragma unroll
        for (int e = 0; e < 8; ++e) {
            float v = (float)((double)tile[kb + e][rl] * rdn);
            hv[e] = f2bf(v);
        }
        size_t base = ((size_t)((b * NT32 + (rb << 1) + tl) * KS + ks)) * 512
                      + ((size_t)lane << 3);
        *(u16x8*)(pk + base) = hv;
    }

    #pragma unroll
    for (int i = 0; i < (CH * NT) / 256; ++i) {
        int flat = tid + i * 256;
        int j = flat / CH, c = flat - j * CH;
        x_rm[(size_t)(b * NPTS + n0 + j) * CH + c] = tile[c][j];
    }
}

// ---------------------------------------------------------------------------
// Phase 1 v16: R19 structure (no-LDS global->reg stream, 32x32x16 swapped
// MFMA, lane owns 1 query) with DEPTH-6 sorted ladder (13 ops/key vs 17).
// 64 buckets/query (cs 32 x h 2) keeps eviction safe at depth 6
// (P ~ C(8,6)/64^6 ~ 4e-10/item). Grid 4096 = B(2) x qb(64) x cs(32).
// ---------------------------------------------------------------------------
__global__ __attribute__((amdgpu_flat_work_group_size(256, 256),
                          amdgpu_waves_per_eu(4, 4)))
void knn_phase1(
    const unsigned short* __restrict__ pk,
    unsigned* __restrict__ cand_p)
{
    const int bid  = blockIdx.x;          // 4096
    const int b    = bid >> 11;
    const int r11  = bid & 2047;
    const int qb   = r11 >> 5;            // query block 0..63 (128 queries)
    const int cs   = r11 & 31;            // cand split 0..31 (256 cands)
    const int tid  = threadIdx.x;
    const int wave = tid >> 6;            // 0..3
    const int lane = tid & 63;
    const unsigned short* pkb = pk + (size_t)b * (NT32 * KS * 512);

    // query fragments (B operand), negated for acc = 4 - inner
    const int qt = qb * 4 + wave;         // query tile32 0..255
    bf16x8 qf[KS];
    #pragma unroll
    for (int ks = 0; ks < KS; ++ks) {
        const unsigned short* p = pkb + ((size_t)(qt * KS + ks)) * 512 + (lane << 3);
        qf[ks] = negbf(*(const bf16x8*)p);
    }
    #pragma unroll
    for (int ks = 0; ks < KS; ++ks)
        asm volatile("" : "+a"(qf[ks]));   // MFMA-only operand: AGPR class

    // sorted-ascending list; sentinels above all real keys (real < 0x40D00000)
    unsigned lst[TLIST];
    #pragma unroll
    for (int t = 0; t < TLIST; ++t) lst[t] = 0xFFFFFF00u | t;

    const unsigned short* gbase = pkb + (size_t)(cs * NITER) * (KS * 512) + (lane << 3);

    for (int it = 0; it < NITER; ++it) {
        const unsigned short* gt = gbase + (size_t)it * (KS * 512);

        f32x16 acc;
        #pragma unroll
        for (int r = 0; r < 16; ++r) acc[r] = 4.f;

        #pragma unroll
        for (int ks = 0; ks < KS; ++ks) {
            bf16x8 cf = *(const bf16x8*)(gt + (ks << 9));
            acc = __builtin_amdgcn_mfma_f32_32x32x16_bf16(cf, qf[ks], acc, 0, 0, 0);
        }

        // sorted-ladder selection: key = 4 - inner (positive -> uint order)
        // packed = (bits & ~0xFF) | (it<<4) | reg ; payload makes keys unique
        const unsigned pb = (unsigned)(it << 4);
        #pragma unroll
        for (int r = 0; r < 16; ++r) {
            unsigned hi = (__float_as_uint(acc[r]) & 0xFFFFFF00u) | pb | (unsigned)r;
            #pragma unroll
            for (int t = 0; t < TLIST; ++t) {
                unsigned lo = umin2(lst[t], hi);
                hi = umax2(lst[t], hi);
                lst[t] = lo;
            }
        }
        // keep list in arch VGPRs at the loop back-edge
        asm volatile("" : "+v"(lst[0]), "+v"(lst[1]), "+v"(lst[2]),
                          "+v"(lst[3]), "+v"(lst[4]), "+v"(lst[5]));
    }

    // write: [B*N query][cs(32)][h(2)][6]  (list sorted ascending; 3x uint2)
    const int query = (qt << 5) + (lane & 31);
    const int h     = lane >> 5;
    unsigned* dst = cand_p + (size_t)(b * NPTS + query) * NCANDP
                    + ((cs << 1) + h) * TLIST;
    *(uint2*)(dst)     = make_uint2(lst[0], lst[1]);
    *(uint2*)(dst + 2) = make_uint2(lst[2], lst[3]);
    *(uint2*)(dst + 4) = make_uint2(lst[4], lst[5]);
}

// ---------------------------------------------------------------------------
// Phase 2: 1 query per wave, 4 per block, 4096 blocks. NSEL=12.
//  (a) per-lane 6 packed cands (one (cs,h) bucket, 3x uint2), sort6 (12 CE),
//      12-round wave-min extraction
//  (b) f64 re-rank (12 cands): lane=(cand,quarter), float4 gathers, 2-shfl
//  (c) parallel rank-of-12: each lane counts lex-smaller keys, writes
//      out[rank] directly
// ---------------------------------------------------------------------------
__global__ __launch_bounds__(256) void knn_phase2(
    const float* __restrict__ x_rm,
    const double* __restrict__ rdnd, const double* __restrict__ ssd,
    const unsigned* __restrict__ cand_p,
    int* __restrict__ out)
{
    __shared__ double xc[P2ROWS][CH];     // 6144 B
    __shared__ int    sel[P2ROWS][16];
    __shared__ double dks[P2ROWS][16];

    const int bi   = blockIdx.x;          // 4096
    const int b    = bi >> 11;
    const int r0   = (bi & 2047) << 2;
    const int tid  = threadIdx.x;
    const int wave = tid >> 6;
    const int lane = tid & 63;
    const int bN   = b * NPTS;

    for (int i = tid; i < P2ROWS * CH; i += 256) {
        int r = i / CH, c = i - r * CH;
        xc[r][c] = (double)x_rm[(size_t)(bN + r0 + r) * CH + c] * rdnd[bN + r0 + r];
    }
    __syncthreads();

    const int row = r0 + wave;

    // (a) lane's bucket: cs = lane>>1, h = lane&1; 6 packed u32 -> u64
    unsigned long long qq[6];
    {
        const unsigned* cp = cand_p + (size_t)(bN + row) * NCANDP + lane * TLIST;
        uint2 v0 = *(const uint2*)cp;
        uint2 v1 = *(const uint2*)(cp + 2);
        uint2 v2 = *(const uint2*)(cp + 4);
        unsigned pk6[6] = {v0.x, v0.y, v1.x, v1.y, v2.x, v2.y};
        const int cs = lane >> 1, h = lane & 1;
        #pragma unroll
        for (int u = 0; u < 6; ++u) {
            unsigned pkv = pk6[u];
            int r = (int)(pkv & 15u), ct = (int)((pkv >> 4) & 7u);
            int rowc = (r & 3) + ((r >> 2) << 3) + (h << 2);
            int col  = (cs << 8) + (ct << 5) + rowc;
            qq[u] = ((unsigned long long)pkv << 32) | (unsigned)col;
        }
        // sort6 ascending, 12-CE network
        unsigned long long t;
        #define CE(a, b) if (qq[b] < qq[a]) { t = qq[a]; qq[a] = qq[b]; qq[b] = t; }
        CE(0,5) CE(1,3) CE(2,4)
        CE(1,2) CE(3,4)
        CE(0,3) CE(2,5)
        CE(0,1) CE(2,3) CE(4,5)
        CE(1,2) CE(3,4)
        #undef CE
    }

    // NSEL extraction rounds of wave-wide u64 min; lane r captures round r
    unsigned long long my_sel = 0;
    #pragma unroll
    for (int round = 0; round < NSEL; ++round) {
        unsigned long long m = qq[0];
        #pragma unroll
        for (int off = 1; off < 64; off <<= 1) {
            unsigned long long o = __shfl_xor(m, off, 64);
            m = (o < m) ? o : m;
        }
        if (qq[0] == m) {                 // exactly one lane (u64 unique via col)
            #pragma unroll
            for (int u = 0; u < 5; ++u) qq[u] = qq[u + 1];
            qq[5] = 0xFFFFFFFFFFFFFFFFull;
        }
        if (lane == round) my_sel = m;
    }
    if (lane < NSEL) sel[wave][lane] = (int)((unsigned)my_sel & 0x3FFFu);
    __builtin_amdgcn_wave_barrier();

    // (b) exact f64 keys: lane = (cand c, quarter qd), c < NSEL active
    {
        const int c = lane & 15, qd = lane >> 4;
        if (c < NSEL) {
            const int m = sel[wave][c];
            const double rdm = rdnd[bN + m];
            const float* xr = x_rm + (size_t)(bN + m) * CH + qd * 48;
            const double* xcp = &xc[wave][qd * 48];
            double s0 = 0.0, s1 = 0.0, s2 = 0.0, s3 = 0.0;
            #pragma unroll
            for (int j = 0; j < 12; ++j) {
                float4 v = *(const float4*)(xr + (j << 2));
                s0 = fma((double)v.x * rdm, xcp[(j << 2) + 0], s0);
                s1 = fma((double)v.y * rdm, xcp[(j << 2) + 1], s1);
                s2 = fma((double)v.z * rdm, xcp[(j << 2) + 2], s2);
                s3 = fma((double)v.w * rdm, xcp[(j << 2) + 3], s3);
            }
            double dot = (s0 + s1) + (s2 + s3);
            dot += __shfl_xor(dot, 16, 64);
            dot += __shfl_xor(dot, 32, 64);
            if (qd == 0) dks[wave][c] = fma(-2.0, dot, ssd[bN + m] * rdm * rdm);
        } else {
            double dot = 0.0;             // keep shuffles wave-uniform
            dot += __shfl_xor(dot, 16, 64);
            dot += __shfl_xor(dot, 32, 64);
        }
    }
    __builtin_amdgcn_wave_barrier();

    // (c) parallel rank: lane c < NSEL counts lex-smaller keys; rank < 9 wins
    if (lane < NSEL) {
        const double dm = dks[wave][lane];
        const int    sm = sel[wave][lane];
        int cnt = 0;
        #pragma unroll
        for (int s = 0; s < NSEL; ++s) {
            double d = dks[wave][s]; int m = sel[wave][s];
            cnt += (d < dm || (d == dm && m < sm)) ? 1 : 0;
        }
        if (cnt < KNN) {
            const int n = row;
            out[(size_t)(bN + n) * KNN + cnt] = sm;
            out[(size_t)BATCH * NPTS * KNN + (size_t)(bN + n) * KNN + cnt] = n;
        }
    }
}

// ---------------------------------------------------------------------------
extern "C" void kernel_launch(void* const* d_in, const int* in_sizes, int n_in,
                              void* d_out, int out_size, void* d_ws, size_t ws_size,
                              hipStream_t stream)
{
    const float* x = (const float*)d_in[0];
    int* out = (int*)d_out;

    char* ws = (char*)d_ws;
    const size_t sz_pk  = (size_t)BATCH * NT32 * KS * 512 * sizeof(unsigned short); // 6.29 MB
    const size_t sz_xrm = (size_t)BATCH * NPTS * CH * sizeof(float);                // 12.58 MB
    const size_t sz_rdn = (size_t)BATCH * NPTS * sizeof(double);
    const size_t sz_ss  = sz_rdn;

    unsigned short* pk = (unsigned short*)(ws);
    float*  x_rm   = (float*) (ws + sz_pk);
    double* rdnd   = (double*)(ws + sz_pk + sz_xrm);
    double* ssd    = (double*)(ws + sz_pk + sz_xrm + sz_rdn);
    unsigned* cand_p = (unsigned*)(ws + sz_pk + sz_xrm + sz_rdn + sz_ss);           // 25.2 MB

    knn_normalize<<<BATCH * (NPTS / NT), 256, 0, stream>>>(x, pk, x_rm, rdnd, ssd);
    knn_phase1  <<<BATCH * 64 * CSPLIT, 256, 0, stream>>>(pk, cand_p);
    knn_phase2  <<<BATCH * (NPTS / P2ROWS), 256, 0, stream>>>(x_rm, rdnd, ssd, cand_p, out);
}

// Round 21
// 143.997 us; speedup vs baseline: 1.0573x; 1.0074x over previous
//
#include <hip/hip_runtime.h>
#include <math.h>

#define BATCH 2
#define CH    192
#define NPTS  8192
#define KNN   9

#define NT     64      // rows per normalize block
#define TLIST  6       // per-lane candidate list depth
#define NT32   256     // 32-wide point tiles per batch
#define KS     12      // 192 / 16
#define CSPLIT 32      // cand-space splits (phase 1)
#define NITER  (NT32 / CSPLIT)   // 8
#define NCANDP 384     // packed candidates per query (32 cs * 2 h * 6)
#define P2ROWS 4       // phase-2 rows per block (1 per wave)
#define NSEL   12      // candidates exactly re-ranked per row

typedef __attribute__((ext_vector_type(8)))  short  bf16x8;
typedef __attribute__((ext_vector_type(8)))  unsigned short u16x8;
typedef __attribute__((ext_vector_type(16))) float  f32x16;

static __device__ __forceinline__ unsigned short f2bf(float f) {
    unsigned u = __float_as_uint(f);
    u += 0x7fffu + ((u >> 16) & 1u);          // round-to-nearest-even
    return (unsigned short)(u >> 16);
}
static __device__ __forceinline__ bf16x8 negbf(bf16x8 v) {
    bf16x8 r;
    #pragma unroll
    for (int e = 0; e < 8; ++e) r[e] = (short)(v[e] ^ (short)0x8000);
    return r;
}
static __device__ __forceinline__ unsigned umax2(unsigned a, unsigned b) {
    return a > b ? a : b;
}
static __device__ __forceinline__ unsigned umin2(unsigned a, unsigned b) {
    return a < b ? a : b;
}

// ---------------------------------------------------------------------------
// Kernel A: norms + layouts (unchanged — passing since R13).
//  pk [B][tile32(256)][ks(12)][lane(64)*8] bf16
//     element: point = tile32*32 + (lane&31), k = ks*16 + (lane>>5)*8 + e
//  x_rm [B][N][C] f32 raw; rdnd/ssd f64 per point.
// ---------------------------------------------------------------------------
__global__ __launch_bounds__(256) void knn_normalize(
    const float* __restrict__ x,
    unsigned short* __restrict__ pk, float* __restrict__ x_rm,
    double* __restrict__ rdnd, double* __restrict__ ssd)
{
    __shared__ float  tile[CH][NT + 1];
    __shared__ double rdn_sh[NT];

    const int b   = blockIdx.x >> 7;
    const int rb  = blockIdx.x & 127;
    const int n0  = rb << 6;
    const int tid = threadIdx.x;
    const float* xb = x + (size_t)b * CH * NPTS;

    #pragma unroll
    for (int i = 0; i < (CH * NT) / 256; ++i) {
        int flat = tid + i * 256;
        int c = flat >> 6, j = flat & 63;
        tile[c][j] = xb[(size_t)c * NPTS + n0 + j];
    }
    __syncthreads();

    // 4 threads per point: quarter q covers dims q*48..q*48+47
    {
        const int j = tid >> 2, q = tid & 3;
        double ss = 0.0;
        #pragma unroll 8
        for (int c = 0; c < 48; ++c) {
            double v = (double)tile[q * 48 + c][j];
            ss = fma(v, v, ss);
        }
        ss += __shfl_xor(ss, 1, 64);
        ss += __shfl_xor(ss, 2, 64);
        if (q == 0) {
            double dn = sqrt(ss);
            if (dn < 1e-12) dn = 1e-12;
            double rdn = 1.0 / dn;
            rdn_sh[j] = rdn;
            rdnd[b * NPTS + n0 + j] = rdn;
            ssd [b * NPTS + n0 + j] = ss;
        }
    }
    __syncthreads();

    // packed MFMA-frag bf16 (2 tile32s * 12 ksteps = 24 frags/block)
    #pragma unroll
    for (int i = 0; i < 6; ++i) {
        int pid  = tid + i * 256;
        int frag = pid >> 6;              // 0..23
        int lane = pid & 63;
        int tl   = frag / KS;             // 0..1
        int ks   = frag - tl * KS;        // 0..11
        int rl   = (tl << 5) + (lane & 31);          // local point 0..63
        int kb   = (ks << 4) + ((lane >> 5) << 3);   // k base
        double rdn = rdn_sh[rl];
        u16x8 hv;
        #pragma unroll
        for (int e = 0; e < 8; ++e) {
            float v = (float)((double)tile[kb + e][rl] * rdn);
            hv[e] = f2bf(v);
        }
        size_t base = ((size_t)((b * NT32 + (rb << 1) + tl) * KS + ks)) * 512
                      + ((size_t)lane << 3);
        *(u16x8*)(pk + base) = hv;
    }

    #pragma unroll
    for (int i = 0; i < (CH * NT) / 256; ++i) {
        int flat = tid + i * 256;
        int j = flat / CH, c = flat - j * CH;
        x_rm[(size_t)(b * NPTS + n0 + j) * CH + c] = tile[c][j];
    }
}

// ---------------------------------------------------------------------------
// Phase 1 v17: identical to R20 except waves_per_eu(4, 8) — R20's (4,4)
// max actively CAPPED residency at 4 waves/SIMD while VGPR=64 permits 8.
// The ladder is a serial dep chain (~48 cyc/key); more resident waves hide
// it. Grid 4096 = B(2) x qb(64) x cs(32); depth-6 sorted ladder; 64
// buckets/query.
// ---------------------------------------------------------------------------
__global__ __attribute__((amdgpu_flat_work_group_size(256, 256),
                          amdgpu_waves_per_eu(4, 8)))
void knn_phase1(
    const unsigned short* __restrict__ pk,
    unsigned* __restrict__ cand_p)
{
    const int bid  = blockIdx.x;          // 4096
    const int b    = bid >> 11;
    const int r11  = bid & 2047;
    const int qb   = r11 >> 5;            // query block 0..63 (128 queries)
    const int cs   = r11 & 31;            // cand split 0..31 (256 cands)
    const int tid  = threadIdx.x;
    const int wave = tid >> 6;            // 0..3
    const int lane = tid & 63;
    const unsigned short* pkb = pk + (size_t)b * (NT32 * KS * 512);

    // query fragments (B operand), negated for acc = 4 - inner
    const int qt = qb * 4 + wave;         // query tile32 0..255
    bf16x8 qf[KS];
    #pragma unroll
    for (int ks = 0; ks < KS; ++ks) {
        const unsigned short* p = pkb + ((size_t)(qt * KS + ks)) * 512 + (lane << 3);
        qf[ks] = negbf(*(const bf16x8*)p);
    }
    #pragma unroll
    for (int ks = 0; ks < KS; ++ks)
        asm volatile("" : "+a"(qf[ks]));   // MFMA-only operand: AGPR class

    // sorted-ascending list; sentinels above all real keys (real < 0x40D00000)
    unsigned lst[TLIST];
    #pragma unroll
    for (int t = 0; t < TLIST; ++t) lst[t] = 0xFFFFFF00u | t;

    const unsigned short* gbase = pkb + (size_t)(cs * NITER) * (KS * 512) + (lane << 3);

    for (int it = 0; it < NITER; ++it) {
        const unsigned short* gt = gbase + (size_t)it * (KS * 512);

        f32x16 acc;
        #pragma unroll
        for (int r = 0; r < 16; ++r) acc[r] = 4.f;

        #pragma unroll
        for (int ks = 0; ks < KS; ++ks) {
            bf16x8 cf = *(const bf16x8*)(gt + (ks << 9));
            acc = __builtin_amdgcn_mfma_f32_32x32x16_bf16(cf, qf[ks], acc, 0, 0, 0);
        }

        // sorted-ladder selection: key = 4 - inner (positive -> uint order)
        // packed = (bits & ~0xFF) | (it<<4) | reg ; payload makes keys unique
        const unsigned pb = (unsigned)(it << 4);
        #pragma unroll
        for (int r = 0; r < 16; ++r) {
            unsigned hi = (__float_as_uint(acc[r]) & 0xFFFFFF00u) | pb | (unsigned)r;
            #pragma unroll
            for (int t = 0; t < TLIST; ++t) {
                unsigned lo = umin2(lst[t], hi);
                hi = umax2(lst[t], hi);
                lst[t] = lo;
            }
        }
        // keep list in arch VGPRs at the loop back-edge
        asm volatile("" : "+v"(lst[0]), "+v"(lst[1]), "+v"(lst[2]),
                          "+v"(lst[3]), "+v"(lst[4]), "+v"(lst[5]));
    }

    // write: [B*N query][cs(32)][h(2)][6]  (list sorted ascending; 3x uint2)
    const int query = (qt << 5) + (lane & 31);
    const int h     = lane >> 5;
    unsigned* dst = cand_p + (size_t)(b * NPTS + query) * NCANDP
                    + ((cs << 1) + h) * TLIST;
    *(uint2*)(dst)     = make_uint2(lst[0], lst[1]);
    *(uint2*)(dst + 2) = make_uint2(lst[2], lst[3]);
    *(uint2*)(dst + 4) = make_uint2(lst[4], lst[5]);
}

// ---------------------------------------------------------------------------
// Phase 2 (unchanged from R20 — passing): 1 query per wave. NSEL=12.
//  (a) per-lane 6 packed cands (one (cs,h) bucket, 3x uint2), sort6 (12 CE),
//      12-round wave-min extraction
//  (b) f64 re-rank (12 cands): lane=(cand,quarter), float4 gathers, 2-shfl
//  (c) parallel rank-of-12: each lane counts lex-smaller keys, writes
//      out[rank] directly
// ---------------------------------------------------------------------------
__global__ __launch_bounds__(256) void knn_phase2(
    const float* __restrict__ x_rm,
    const double* __restrict__ rdnd, const double* __restrict__ ssd,
    const unsigned* __restrict__ cand_p,
    int* __restrict__ out)
{
    __shared__ double xc[P2ROWS][CH];     // 6144 B
    __shared__ int    sel[P2ROWS][16];
    __shared__ double dks[P2ROWS][16];

    const int bi   = blockIdx.x;          // 4096
    const int b    = bi >> 11;
    const int r0   = (bi & 2047) << 2;
    const int tid  = threadIdx.x;
    const int wave = tid >> 6;
    const int lane = tid & 63;
    const int bN   = b * NPTS;

    for (int i = tid; i < P2ROWS * CH; i += 256) {
        int r = i / CH, c = i - r * CH;
        xc[r][c] = (double)x_rm[(size_t)(bN + r0 + r) * CH + c] * rdnd[bN + r0 + r];
    }
    __syncthreads();

    const int row = r0 + wave;

    // (a) lane's bucket: cs = lane>>1, h = lane&1; 6 packed u32 -> u64
    unsigned long long qq[6];
    {
        const unsigned* cp = cand_p + (size_t)(bN + row) * NCANDP + lane * TLIST;
        uint2 v0 = *(const uint2*)cp;
        uint2 v1 = *(const uint2*)(cp + 2);
        uint2 v2 = *(const uint2*)(cp + 4);
        unsigned pk6[6] = {v0.x, v0.y, v1.x, v1.y, v2.x, v2.y};
        const int cs = lane >> 1, h = lane & 1;
        #pragma unroll
        for (int u = 0; u < 6; ++u) {
            unsigned pkv = pk6[u];
            int r = (int)(pkv & 15u), ct = (int)((pkv >> 4) & 7u);
            int rowc = (r & 3) + ((r >> 2) << 3) + (h << 2);
            int col  = (cs << 8) + (ct << 5) + rowc;
            qq[u] = ((unsigned long long)pkv << 32) | (unsigned)col;
        }
        // sort6 ascending, 12-CE network
        unsigned long long t;
        #define CE(a, b) if (qq[b] < qq[a]) { t = qq[a]; qq[a] = qq[b]; qq[b] = t; }
        CE(0,5) CE(1,3) CE(2,4)
        CE(1,2) CE(3,4)
        CE(0,3) CE(2,5)
        CE(0,1) CE(2,3) CE(4,5)
        CE(1,2) CE(3,4)
        #undef CE
    }

    // NSEL extraction rounds of wave-wide u64 min; lane r captures round r
    unsigned long long my_sel = 0;
    #pragma unroll
    for (int round = 0; round < NSEL; ++round) {
        unsigned long long m = qq[0];
        #pragma unroll
        for (int off = 1; off < 64; off <<= 1) {
            unsigned long long o = __shfl_xor(m, off, 64);
            m = (o < m) ? o : m;
        }
        if (qq[0] == m) {                 // exactly one lane (u64 unique via col)
            #pragma unroll
            for (int u = 0; u < 5; ++u) qq[u] = qq[u + 1];
            qq[5] = 0xFFFFFFFFFFFFFFFFull;
        }
        if (lane == round) my_sel = m;
    }
    if (lane < NSEL) sel[wave][lane] = (int)((unsigned)my_sel & 0x3FFFu);
    __builtin_amdgcn_wave_barrier();

    // (b) exact f64 keys: lane = (cand c, quarter qd), c < NSEL active
    {
        const int c = lane & 15, qd = lane >> 4;
        if (c < NSEL) {
            const int m = sel[wave][c];
            const double rdm = rdnd[bN + m];
            const float* xr = x_rm + (size_t)(bN + m) * CH + qd * 48;
            const double* xcp = &xc[wave][qd * 48];
            double s0 = 0.0, s1 = 0.0, s2 = 0.0, s3 = 0.0;
            #pragma unroll
            for (int j = 0; j < 12; ++j) {
                float4 v = *(const float4*)(xr + (j << 2));
                s0 = fma((double)v.x * rdm, xcp[(j << 2) + 0], s0);
                s1 = fma((double)v.y * rdm, xcp[(j << 2) + 1], s1);
                s2 = fma((double)v.z * rdm, xcp[(j << 2) + 2], s2);
                s3 = fma((double)v.w * rdm, xcp[(j << 2) + 3], s3);
            }
            double dot = (s0 + s1) + (s2 + s3);
            dot += __shfl_xor(dot, 16, 64);
            dot += __shfl_xor(dot, 32, 64);
            if (qd == 0) dks[wave][c] = fma(-2.0, dot, ssd[bN + m] * rdm * rdm);
        } else {
            double dot = 0.0;             // keep shuffles wave-uniform
            dot += __shfl_xor(dot, 16, 64);
            dot += __shfl_xor(dot, 32, 64);
        }
    }
    __builtin_amdgcn_wave_barrier();

    // (c) parallel rank: lane c < NSEL counts lex-smaller keys; rank < 9 wins
    if (lane < NSEL) {
        const double dm = dks[wave][lane];
        const int    sm = sel[wave][lane];
        int cnt = 0;
        #pragma unroll
        for (int s = 0; s < NSEL; ++s) {
            double d = dks[wave][s]; int m = sel[wave][s];
            cnt += (d < dm || (d == dm && m < sm)) ? 1 : 0;
        }
        if (cnt < KNN) {
            const int n = row;
            out[(size_t)(bN + n) * KNN + cnt] = sm;
            out[(size_t)BATCH * NPTS * KNN + (size_t)(bN + n) * KNN + cnt] = n;
        }
    }
}

// ---------------------------------------------------------------------------
extern "C" void kernel_launch(void* const* d_in, const int* in_sizes, int n_in,
                              void* d_out, int out_size, void* d_ws, size_t ws_size,
                              hipStream_t stream)
{
    const float* x = (const float*)d_in[0];
    int* out = (int*)d_out;

    char* ws = (char*)d_ws;
    const size_t sz_pk  = (size_t)BATCH * NT32 * KS * 512 * sizeof(unsigned short); // 6.29 MB
    const size_t sz_xrm = (size_t)BATCH * NPTS * CH * sizeof(float);                // 12.58 MB
    const size_t sz_rdn = (size_t)BATCH * NPTS * sizeof(double);
    const size_t sz_ss  = sz_rdn;

    unsigned short* pk = (unsigned short*)(ws);
    float*  x_rm   = (float*) (ws + sz_pk);
    double* rdnd   = (double*)(ws + sz_pk + sz_xrm);
    double* ssd    = (double*)(ws + sz_pk + sz_xrm + sz_rdn);
    unsigned* cand_p = (unsigned*)(ws + sz_pk + sz_xrm + sz_rdn + sz_ss);           // 25.2 MB

    knn_normalize<<<BATCH * (NPTS / NT), 256, 0, stream>>>(x, pk, x_rm, rdnd, ssd);
    knn_phase1  <<<BATCH * 64 * CSPLIT, 256, 0, stream>>>(pk, cand_p);
    knn_phase2  <<<BATCH * (NPTS / P2ROWS), 256, 0, stream>>>(x_rm, rdnd, ssd, cand_p, out);
}